// Round 3
// baseline (112.600 us; speedup 1.0000x reference)
//
#include <hip/hip_runtime.h>
#include <math.h>

#define BB 64
#define WW 128   // K (input feature dim per node)
#define FF 64    // nodes
#define HH 4
#define OW 128   // D (per-head output dim)

// ---------------------------------------------------------------------------
// Fully fused GAT, v3: LDS-pipe-instruction minimization.
// Round-2 analysis: kernel is bound on the per-CU LDS pipe (~93K cyc of
// ds_read slots vs ~16K of FMA issue). Occupancy/waves are NOT the limiter.
//
// Changes vs v2:
//  - Phase A: 8i x 8d register tile on 256 threads (4 waves). LDS instrs per
//    256 FMA drop 32 -> 16 (x-reads are 4-address multicasts, W-reads b128
//    spanning 4k). W d-rows strided d = dg + 16e: a wave's 16 simultaneous
//    rows are consecutive -> banks 4 apart, 2-way (free). Both K-halves
//    accumulate in regs (no partial reduce). ~49K -> ~20K pipe cycles.
//  - Phase D: 8 waves x 8 j (was 16 x 4): broadcast fd reads amortized 2x.
//  - Phase F: 8 waves x 16 d (was 16 x 8): broadcast fs reads amortized 2x;
//    inv-l computed per-thread (no extra barrier).
//  - Idle waves in A/D/F just hit the barriers; LDS pipe is the bottleneck,
//    so parked waves cost nothing.
// ---------------------------------------------------------------------------

struct GemmRegion {
    float xq[64 * 64];          // [k-half 64][i 64]        16 KB
    float wq[2 * 128 * 68];     // [(m*128+d)][k 64 pad 68] 69.6 KB
};
struct AttnRegion {
    float fsl[FF * 132];        // [i][d] pad 132
    float fdl[FF * 132];        // [j][d] pad 132
    float st[FF * 68];          // [i][j] pad 68
    float A6[OW], B4[OW];       // 0.6*a_d, 0.4*a_d
    float redm[16 * 64];        // cs/cd partials, then strip maxes
    float reds[16 * 64];        // strip sums
};
union SMem { GemmRegion g; AttnRegion a; };

__global__ __launch_bounds__(1024, 4) void gat_fused(
    const float* __restrict__ x,     // [B][128 k][64 i]
    const float* __restrict__ Wsrc,  // [512][128]
    const float* __restrict__ bsrc,
    const float* __restrict__ Wdst,
    const float* __restrict__ bdst,
    const float* __restrict__ attn,  // [H][128]
    float* __restrict__ out)         // [B][128 d][64 j], pre-zeroed
{
    __shared__ __align__(16) SMem sm;
    __shared__ float bl[2 * 128];

    const int bx = blockIdx.x;
    const int h  = bx & 3;
    const int b  = bx >> 2;
    const int t  = threadIdx.x;

    // ---- phase A thread map (t < 256): m | ig(8) | dg(16) ----
    // thread outputs: i = ig*8 .. +7,  d = dg + 16*e (e = 0..7)
    const int m  = t >> 7;
    const int ig = (t >> 4) & 7;
    const int dg = t & 15;
    const int i0 = ig * 8;

    if (t < 256) bl[t] = (t & 128 ? bdst : bsrc)[h * 128 + (t & 127)];

    float acc[8][8] = {};            // [ii][e]

    for (int kh = 0; kh < 2; ++kh) {
        if (kh) __syncthreads();
        // stage x half: [64 k][64 i] = 1024 float4, 1 per thread, coalesced
        {
            const int k = t >> 4, iq = t & 15;
            *(float4*)&sm.g.xq[k * 64 + iq * 4] =
                *(const float4*)(x + ((size_t)b * WW + kh * 64 + k) * FF + iq * 4);
        }
        // stage W half: 2 mats x 128 d x 16 quads = 4096 float4
        #pragma unroll
        for (int p = 0; p < 4; ++p) {
            const int idx = p * 1024 + t;
            const int mm = idx >> 11, d = (idx >> 4) & 127, q = idx & 15;
            *(float4*)&sm.g.wq[(mm * 128 + d) * 68 + q * 4] =
                *(const float4*)((mm ? Wdst : Wsrc)
                                 + (size_t)(h * 128 + d) * WW + kh * 64 + q * 4);
        }
        __syncthreads();

        if (t < 256) {
            #pragma unroll 2
            for (int k0 = 0; k0 < 64; k0 += 4) {
                float4 xv[8];                       // [kk][half-of-8i]
                #pragma unroll
                for (int kk = 0; kk < 4; ++kk) {
                    xv[kk * 2 + 0] = *(const float4*)&sm.g.xq[(k0 + kk) * 64 + i0];
                    xv[kk * 2 + 1] = *(const float4*)&sm.g.xq[(k0 + kk) * 64 + i0 + 4];
                }
                #pragma unroll
                for (int e = 0; e < 8; ++e) {
                    const float4 wv =
                        *(const float4*)&sm.g.wq[(m * 128 + dg + 16 * e) * 68 + k0];
                    #pragma unroll
                    for (int kk = 0; kk < 4; ++kk) {
                        const float wf = ((const float*)&wv)[kk];
                        const float* xa = (const float*)&xv[kk * 2];
                        const float* xb = (const float*)&xv[kk * 2 + 1];
                        acc[0][e] = fmaf(xa[0], wf, acc[0][e]);
                        acc[1][e] = fmaf(xa[1], wf, acc[1][e]);
                        acc[2][e] = fmaf(xa[2], wf, acc[2][e]);
                        acc[3][e] = fmaf(xa[3], wf, acc[3][e]);
                        acc[4][e] = fmaf(xb[0], wf, acc[4][e]);
                        acc[5][e] = fmaf(xb[1], wf, acc[5][e]);
                        acc[6][e] = fmaf(xb[2], wf, acc[6][e]);
                        acc[7][e] = fmaf(xb[3], wf, acc[7][e]);
                    }
                }
            }
        }
    }
    __syncthreads();   // GEMM region dead; attn region may now be written

    // ------------- phase B: acc+bias -> fsl/fdl, stage A6/B4 -------------
    if (t < 256) {
        float* dst = m ? sm.a.fdl : sm.a.fsl;
        #pragma unroll
        for (int e = 0; e < 8; ++e) {
            const int d = dg + 16 * e;
            const float bv = bl[m * 128 + d];
            #pragma unroll
            for (int ii = 0; ii < 8; ++ii)
                dst[(i0 + ii) * 132 + d] = acc[ii][e] + bv;
        }
    }
    if (t < 128) {
        const float av = attn[h * OW + t];
        sm.a.A6[t] = 0.6f * av;
        sm.a.B4[t] = 0.4f * av;
    }
    __syncthreads();

    // --------- phase C: cs/cd partials (256 threads, 2 halves each) ------
    // redm[sel*64+i]: sel 0,1 = fs halves; 2,3 = fd halves. Summed in D.
    if (t < 256) {
        const int i = t & 63, sel = t >> 6;
        const float* src = (sel < 2 ? sm.a.fsl : sm.a.fdl) + i * 132 + (sel & 1) * 64;
        const float* a6  = sm.a.A6 + (sel & 1) * 64;
        float s = 0.0f;
        #pragma unroll
        for (int c = 0; c < 16; ++c) {
            float4 fv = *(const float4*)&src[c * 4];
            float4 av = *(const float4*)&a6[c * 4];
            s = fmaf(fv.x, av.x, fmaf(fv.y, av.y, fmaf(fv.z, av.z, fmaf(fv.w, av.w, s))));
        }
        sm.a.redm[sel * 64 + i] = s;
    }
    __syncthreads();

    // ------------------- phase D: scores (8 waves x 8 j) -----------------
    if (t < 512) {
        const int lane = t & 63;              // i
        const int jl0  = (t >> 6) * 8;
        float sc[8] = {};
        #pragma unroll 4
        for (int c = 0; c < 32; ++c) {
            const int dd0 = c * 4;
            float4 fsv = *(const float4*)&sm.a.fsl[lane * 132 + dd0];   // per-lane
            float4 b4  = *(const float4*)&sm.a.B4[dd0];                 // bcast
            #pragma unroll
            for (int jj = 0; jj < 8; ++jj) {
                float4 fdv = *(const float4*)&sm.a.fdl[(jl0 + jj) * 132 + dd0]; // bcast
                float r = sc[jj];
                r = fmaf(b4.x, fabsf(fsv.x + fdv.x), r);
                r = fmaf(b4.y, fabsf(fsv.y + fdv.y), r);
                r = fmaf(b4.z, fabsf(fsv.z + fdv.z), r);
                r = fmaf(b4.w, fabsf(fsv.w + fdv.w), r);
                sc[jj] = r;
            }
        }
        const float csl = sm.a.redm[lane] + sm.a.redm[64 + lane];
        float4 o0, o1;
        o0.x = sc[0] + csl + sm.a.redm[128 + jl0 + 0] + sm.a.redm[192 + jl0 + 0];
        o0.y = sc[1] + csl + sm.a.redm[128 + jl0 + 1] + sm.a.redm[192 + jl0 + 1];
        o0.z = sc[2] + csl + sm.a.redm[128 + jl0 + 2] + sm.a.redm[192 + jl0 + 2];
        o0.w = sc[3] + csl + sm.a.redm[128 + jl0 + 3] + sm.a.redm[192 + jl0 + 3];
        o1.x = sc[4] + csl + sm.a.redm[128 + jl0 + 4] + sm.a.redm[192 + jl0 + 4];
        o1.y = sc[5] + csl + sm.a.redm[128 + jl0 + 5] + sm.a.redm[192 + jl0 + 5];
        o1.z = sc[6] + csl + sm.a.redm[128 + jl0 + 6] + sm.a.redm[192 + jl0 + 6];
        o1.w = sc[7] + csl + sm.a.redm[128 + jl0 + 7] + sm.a.redm[192 + jl0 + 7];
        *(float4*)&sm.a.st[lane * 68 + jl0]     = o0;
        *(float4*)&sm.a.st[lane * 68 + jl0 + 4] = o1;
    }
    __syncthreads();

    // ------------------- phase E: softmax over i per j -------------------
    {   // E1: per-strip max (16 strips of 4 i)
        const int j = t & 63, s = t >> 6;
        const int i0s = s * 4;
        float mx = sm.a.st[i0s * 68 + j];
        #pragma unroll
        for (int k = 1; k < 4; ++k) mx = fmaxf(mx, sm.a.st[(i0s + k) * 68 + j]);
        sm.a.redm[s * 64 + j] = mx;
    }
    __syncthreads();
    {   // E2: global max, exp in place, per-strip sum
        const int j = t & 63, s = t >> 6;
        const int i0s = s * 4;
        float mj = sm.a.redm[j];
        #pragma unroll
        for (int s2 = 1; s2 < 16; ++s2) mj = fmaxf(mj, sm.a.redm[s2 * 64 + j]);
        float ps = 0.0f;
        #pragma unroll
        for (int k = 0; k < 4; ++k) {
            float e = __expf(sm.a.st[(i0s + k) * 68 + j] - mj);
            sm.a.st[(i0s + k) * 68 + j] = e;
            ps += e;
        }
        sm.a.reds[s * 64 + j] = ps;
    }
    __syncthreads();

    // --------- phase F: aggregation (8 waves x 16 d) + atomic out --------
    if (t < 512) {
        const int j = t & 63, dblk = t >> 6;     // dblk 0..7, 16 d each
        float l = 0.0f;
        #pragma unroll
        for (int s2 = 0; s2 < 16; ++s2) l += sm.a.reds[s2 * 64 + j];
        const float iv = 0.25f / l;              // head-mean folded in

        float ag[16] = {};
        #pragma unroll 4
        for (int i = 0; i < FF; ++i) {
            const float p = sm.a.st[i * 68 + j];            // per-lane, stride-1
            const float* fr = &sm.a.fsl[i * 132 + dblk * 16];  // wave-uniform
            float4 f0 = *(const float4*)(fr);
            float4 f1 = *(const float4*)(fr + 4);
            float4 f2 = *(const float4*)(fr + 8);
            float4 f3 = *(const float4*)(fr + 12);
            ag[0]  = fmaf(p, f0.x, ag[0]);  ag[1]  = fmaf(p, f0.y, ag[1]);
            ag[2]  = fmaf(p, f0.z, ag[2]);  ag[3]  = fmaf(p, f0.w, ag[3]);
            ag[4]  = fmaf(p, f1.x, ag[4]);  ag[5]  = fmaf(p, f1.y, ag[5]);
            ag[6]  = fmaf(p, f1.z, ag[6]);  ag[7]  = fmaf(p, f1.w, ag[7]);
            ag[8]  = fmaf(p, f2.x, ag[8]);  ag[9]  = fmaf(p, f2.y, ag[9]);
            ag[10] = fmaf(p, f2.z, ag[10]); ag[11] = fmaf(p, f2.w, ag[11]);
            ag[12] = fmaf(p, f3.x, ag[12]); ag[13] = fmaf(p, f3.y, ag[13]);
            ag[14] = fmaf(p, f3.z, ag[14]); ag[15] = fmaf(p, f3.w, ag[15]);
        }
        float* ob = out + ((size_t)b * OW + dblk * 16) * FF + j;
        #pragma unroll
        for (int e = 0; e < 16; ++e)
            atomicAdd(ob + e * FF, ag[e] * iv);
    }
}

// ---------------------------------------------------------------------------
extern "C" void kernel_launch(void* const* d_in, const int* in_sizes, int n_in,
                              void* d_out, int out_size, void* d_ws, size_t ws_size,
                              hipStream_t stream) {
    const float* x    = (const float*)d_in[0];
    const float* Wsrc = (const float*)d_in[1];
    const float* bsrc = (const float*)d_in[2];
    const float* Wdst = (const float*)d_in[3];
    const float* bdst = (const float*)d_in[4];
    const float* attn = (const float*)d_in[5];

    hipMemsetAsync(d_out, 0, (size_t)out_size, stream);
    gat_fused<<<BB * HH, 1024, 0, stream>>>(x, Wsrc, bsrc, Wdst, bdst, attn,
                                            (float*)d_out);
}

// Round 4
// 105.151 us; speedup vs baseline: 1.0708x; 1.0708x over previous
//
#include <hip/hip_runtime.h>
#include <math.h>

#define BB 64
#define WW 128   // K (input feature dim per node)
#define FF 64    // nodes
#define HH 4
#define OW 128   // D (per-head output dim)

// ---------------------------------------------------------------------------
// Fully fused GAT, v4: v3's LDS-instruction reduction done RIGHT (no spill).
// Round-3 post-mortem: the 8x8 register tile spilled (VGPR stuck at 64,
// WRITE_SIZE 13->33.5 MB = scratch traffic) because the allocator's
// occupancy heuristic ignores the LDS limit (93 KB -> 1 block/CU) and
// targeted 8 waves/SIMD. Fix:
//   - 512-thread block (8 waves; 2/SIMD) -> per-wave VGPR ceiling 256.
//   - amdgpu_waves_per_eu(2,2) pins the allocator target -> ~115 regs used,
//     no scratch.
// Structure:
//   A) GEMM on 256 threads, 8i x 8d tile: 2048 ds_read_b128 total
//      (vs 4096 in v2) -> LDS pipe ~10 us. W rows d = dg + 16e: a wave's 16
//      simultaneous rows are 4 banks apart spanning all 32 -> 2-way (free).
//      xq padded to 68 so staging writes are ~2-way too.
//   B) epilogue: acc+bias -> fsl/fdl (b32 scatter, 4-way, tiny instr count)
//   C) cs/cd partials on 256 threads
//   D) scores: 8 waves x 8 j (lane = i); fd/B4 reads wave-uniform broadcasts
//   E) softmax over i per j: 8 strips of 8
//   F) aggregation: 8 waves x 16 d, atomicAdd 256B segments into out
// ---------------------------------------------------------------------------

struct GemmRegion {
    float xq[64 * 68];          // [k-half 64][i 64 pad 68] 17.4 KB
    float wq[2 * 128 * 68];     // [(m*128+d)][k 64 pad 68] 69.6 KB
};
struct AttnRegion {
    float fsl[FF * 132];        // [i][d] pad 132
    float fdl[FF * 132];        // [j][d] pad 132
    float st[FF * 68];          // [i][j] pad 68
    float A6[OW], B4[OW];       // 0.6*a_d, 0.4*a_d
    float redm[8 * 64];         // cs/cd partials (sel<4), then strip maxes
    float reds[8 * 64];         // strip sums
};
union SMem { GemmRegion g; AttnRegion a; };

__global__ void __launch_bounds__(512)
__attribute__((amdgpu_waves_per_eu(2, 2)))
gat_fused(
    const float* __restrict__ x,     // [B][128 k][64 i]
    const float* __restrict__ Wsrc,  // [512][128]
    const float* __restrict__ bsrc,
    const float* __restrict__ Wdst,
    const float* __restrict__ bdst,
    const float* __restrict__ attn,  // [H][128]
    float* __restrict__ out)         // [B][128 d][64 j], pre-zeroed
{
    __shared__ __align__(16) SMem sm;
    __shared__ float bl[2 * 128];

    const int bx = blockIdx.x;
    const int h  = bx & 3;
    const int b  = bx >> 2;
    const int t  = threadIdx.x;

    // ---- phase A thread map (t < 256): m | ig(8) | dg(16) ----
    // outputs: i = ig*8 .. +7,  d = dg + 16*e (e = 0..7)
    const int m  = t >> 7;
    const int ig = (t >> 4) & 7;
    const int dg = t & 15;
    const int i0 = ig * 8;

    if (t < 256) bl[t] = (t & 128 ? bdst : bsrc)[h * 128 + (t & 127)];

    float acc[8][8] = {};            // [ii][e]

    for (int kh = 0; kh < 2; ++kh) {
        if (kh) __syncthreads();
        // stage x half: [64 k][64 i] = 1024 float4, 2 per thread
        #pragma unroll
        for (int p = 0; p < 2; ++p) {
            const int idx = p * 512 + t;
            const int k = idx >> 4, iq = idx & 15;
            *(float4*)&sm.g.xq[k * 68 + iq * 4] =
                *(const float4*)(x + ((size_t)b * WW + kh * 64 + k) * FF + iq * 4);
        }
        // stage W half: 2 mats x 128 d x 16 quads = 4096 float4, 8 per thread
        #pragma unroll
        for (int p = 0; p < 8; ++p) {
            const int idx = p * 512 + t;
            const int mm = idx >> 11, d = (idx >> 4) & 127, q = idx & 15;
            *(float4*)&sm.g.wq[(mm * 128 + d) * 68 + q * 4] =
                *(const float4*)((mm ? Wdst : Wsrc)
                                 + (size_t)(h * 128 + d) * WW + kh * 64 + q * 4);
        }
        __syncthreads();

        if (t < 256) {
            #pragma unroll 1
            for (int k0 = 0; k0 < 64; k0 += 4) {
                float4 wv[8];
                #pragma unroll
                for (int e = 0; e < 8; ++e)
                    wv[e] = *(const float4*)&sm.g.wq[(m * 128 + dg + 16 * e) * 68 + k0];
                #pragma unroll
                for (int kk = 0; kk < 4; ++kk) {
                    const float4 xa = *(const float4*)&sm.g.xq[(k0 + kk) * 68 + i0];
                    const float4 xb = *(const float4*)&sm.g.xq[(k0 + kk) * 68 + i0 + 4];
                    #pragma unroll
                    for (int e = 0; e < 8; ++e) {
                        const float wf = ((const float*)&wv[e])[kk];
                        acc[0][e] = fmaf(xa.x, wf, acc[0][e]);
                        acc[1][e] = fmaf(xa.y, wf, acc[1][e]);
                        acc[2][e] = fmaf(xa.z, wf, acc[2][e]);
                        acc[3][e] = fmaf(xa.w, wf, acc[3][e]);
                        acc[4][e] = fmaf(xb.x, wf, acc[4][e]);
                        acc[5][e] = fmaf(xb.y, wf, acc[5][e]);
                        acc[6][e] = fmaf(xb.z, wf, acc[6][e]);
                        acc[7][e] = fmaf(xb.w, wf, acc[7][e]);
                    }
                }
            }
        }
    }
    __syncthreads();   // GEMM region dead; attn region may now be written

    // ------------- phase B: acc+bias -> fsl/fdl, stage A6/B4 -------------
    if (t < 256) {
        float* dst = m ? sm.a.fdl : sm.a.fsl;
        #pragma unroll
        for (int e = 0; e < 8; ++e) {
            const int d = dg + 16 * e;
            const float bv = bl[m * 128 + d];
            #pragma unroll
            for (int ii = 0; ii < 8; ++ii)
                dst[(i0 + ii) * 132 + d] = acc[ii][e] + bv;
        }
    }
    if (t < 128) {
        const float av = attn[h * OW + t];
        sm.a.A6[t] = 0.6f * av;
        sm.a.B4[t] = 0.4f * av;
    }
    __syncthreads();

    // --------- phase C: cs/cd partials (256 threads, 2 halves each) ------
    // redm[sel*64+i]: sel 0,1 = fs halves; 2,3 = fd halves. Summed in D.
    if (t < 256) {
        const int i = t & 63, sel = t >> 6;
        const float* src = (sel < 2 ? sm.a.fsl : sm.a.fdl) + i * 132 + (sel & 1) * 64;
        const float* a6  = sm.a.A6 + (sel & 1) * 64;
        float s = 0.0f;
        #pragma unroll
        for (int c = 0; c < 16; ++c) {
            float4 fv = *(const float4*)&src[c * 4];
            float4 av = *(const float4*)&a6[c * 4];
            s = fmaf(fv.x, av.x, fmaf(fv.y, av.y, fmaf(fv.z, av.z, fmaf(fv.w, av.w, s))));
        }
        sm.a.redm[sel * 64 + i] = s;
    }
    __syncthreads();

    // ------------------- phase D: scores (8 waves x 8 j) -----------------
    {
        const int lane = t & 63;              // i
        const int jl0  = (t >> 6) * 8;
        float sc[8] = {};
        #pragma unroll 4
        for (int c = 0; c < 32; ++c) {
            const int dd0 = c * 4;
            float4 fsv = *(const float4*)&sm.a.fsl[lane * 132 + dd0];   // per-lane
            float4 b4  = *(const float4*)&sm.a.B4[dd0];                 // bcast
            #pragma unroll
            for (int jj = 0; jj < 8; ++jj) {
                float4 fdv = *(const float4*)&sm.a.fdl[(jl0 + jj) * 132 + dd0]; // bcast
                float r = sc[jj];
                r = fmaf(b4.x, fabsf(fsv.x + fdv.x), r);
                r = fmaf(b4.y, fabsf(fsv.y + fdv.y), r);
                r = fmaf(b4.z, fabsf(fsv.z + fdv.z), r);
                r = fmaf(b4.w, fabsf(fsv.w + fdv.w), r);
                sc[jj] = r;
            }
        }
        const float csl = sm.a.redm[lane] + sm.a.redm[64 + lane];
        float4 o0, o1;
        o0.x = sc[0] + csl + sm.a.redm[128 + jl0 + 0] + sm.a.redm[192 + jl0 + 0];
        o0.y = sc[1] + csl + sm.a.redm[128 + jl0 + 1] + sm.a.redm[192 + jl0 + 1];
        o0.z = sc[2] + csl + sm.a.redm[128 + jl0 + 2] + sm.a.redm[192 + jl0 + 2];
        o0.w = sc[3] + csl + sm.a.redm[128 + jl0 + 3] + sm.a.redm[192 + jl0 + 3];
        o1.x = sc[4] + csl + sm.a.redm[128 + jl0 + 4] + sm.a.redm[192 + jl0 + 4];
        o1.y = sc[5] + csl + sm.a.redm[128 + jl0 + 5] + sm.a.redm[192 + jl0 + 5];
        o1.z = sc[6] + csl + sm.a.redm[128 + jl0 + 6] + sm.a.redm[192 + jl0 + 6];
        o1.w = sc[7] + csl + sm.a.redm[128 + jl0 + 7] + sm.a.redm[192 + jl0 + 7];
        *(float4*)&sm.a.st[lane * 68 + jl0]     = o0;
        *(float4*)&sm.a.st[lane * 68 + jl0 + 4] = o1;
    }
    __syncthreads();

    // --------------- phase E: softmax over i per j (8 strips) ------------
    {   // E1: per-strip max (8 strips of 8 i)
        const int j = t & 63, s = t >> 6;
        const int i0s = s * 8;
        float mx = sm.a.st[i0s * 68 + j];
        #pragma unroll
        for (int k = 1; k < 8; ++k) mx = fmaxf(mx, sm.a.st[(i0s + k) * 68 + j]);
        sm.a.redm[s * 64 + j] = mx;
    }
    __syncthreads();
    {   // E2: global max, exp in place, per-strip sum
        const int j = t & 63, s = t >> 6;
        const int i0s = s * 8;
        float mj = sm.a.redm[j];
        #pragma unroll
        for (int s2 = 1; s2 < 8; ++s2) mj = fmaxf(mj, sm.a.redm[s2 * 64 + j]);
        float ps = 0.0f;
        #pragma unroll
        for (int k = 0; k < 8; ++k) {
            float e = __expf(sm.a.st[(i0s + k) * 68 + j] - mj);
            sm.a.st[(i0s + k) * 68 + j] = e;
            ps += e;
        }
        sm.a.reds[s * 64 + j] = ps;
    }
    __syncthreads();

    // --------- phase F: aggregation (8 waves x 16 d) + atomic out --------
    {
        const int j = t & 63, dblk = t >> 6;     // dblk 0..7, 16 d each
        float l = 0.0f;
        #pragma unroll
        for (int s2 = 0; s2 < 8; ++s2) l += sm.a.reds[s2 * 64 + j];
        const float iv = 0.25f / l;              // head-mean folded in

        float ag[16] = {};
        #pragma unroll 4
        for (int i = 0; i < FF; ++i) {
            const float p = sm.a.st[i * 68 + j];               // per-lane stride-1
            const float* fr = &sm.a.fsl[i * 132 + dblk * 16];  // wave-uniform
            float4 f0 = *(const float4*)(fr);
            float4 f1 = *(const float4*)(fr + 4);
            float4 f2 = *(const float4*)(fr + 8);
            float4 f3 = *(const float4*)(fr + 12);
            ag[0]  = fmaf(p, f0.x, ag[0]);  ag[1]  = fmaf(p, f0.y, ag[1]);
            ag[2]  = fmaf(p, f0.z, ag[2]);  ag[3]  = fmaf(p, f0.w, ag[3]);
            ag[4]  = fmaf(p, f1.x, ag[4]);  ag[5]  = fmaf(p, f1.y, ag[5]);
            ag[6]  = fmaf(p, f1.z, ag[6]);  ag[7]  = fmaf(p, f1.w, ag[7]);
            ag[8]  = fmaf(p, f2.x, ag[8]);  ag[9]  = fmaf(p, f2.y, ag[9]);
            ag[10] = fmaf(p, f2.z, ag[10]); ag[11] = fmaf(p, f2.w, ag[11]);
            ag[12] = fmaf(p, f3.x, ag[12]); ag[13] = fmaf(p, f3.y, ag[13]);
            ag[14] = fmaf(p, f3.z, ag[14]); ag[15] = fmaf(p, f3.w, ag[15]);
        }
        float* ob = out + ((size_t)b * OW + dblk * 16) * FF + j;
        #pragma unroll
        for (int e = 0; e < 16; ++e)
            atomicAdd(ob + e * FF, ag[e] * iv);
    }
}

// ---------------------------------------------------------------------------
extern "C" void kernel_launch(void* const* d_in, const int* in_sizes, int n_in,
                              void* d_out, int out_size, void* d_ws, size_t ws_size,
                              hipStream_t stream) {
    const float* x    = (const float*)d_in[0];
    const float* Wsrc = (const float*)d_in[1];
    const float* bsrc = (const float*)d_in[2];
    const float* Wdst = (const float*)d_in[3];
    const float* bdst = (const float*)d_in[4];
    const float* attn = (const float*)d_in[5];

    hipMemsetAsync(d_out, 0, (size_t)out_size, stream);
    gat_fused<<<BB * HH, 512, 0, stream>>>(x, Wsrc, bsrc, Wdst, bdst, attn,
                                           (float*)d_out);
}